// Round 1
// baseline (119.014 us; speedup 1.0000x reference)
//
#include <hip/hip_runtime.h>

// Minkowski 3x3 stride-2 sum pooling, applied 3x.
// feat: (4,1024,1024,16) f32, mask: (4,1024,1024) int32 (bool 0/1)
// out = concat(c2 flat, c3 flat); c1/m1/m2 staged in d_ws.

constexpr int BATCH = 4;

template <int H_IN, int W_IN, bool APPLY_MASK, typename MaskT>
__global__ __launch_bounds__(256) void pool3x3s2(
    const float* __restrict__ in, const MaskT* __restrict__ msk,
    float* __restrict__ out, unsigned char* __restrict__ mout)
{
    constexpr int HO = H_IN / 2, WO = W_IN / 2;
    const int tid = blockIdx.x * 256 + threadIdx.x;

    const int c4 = tid & 3;   // which float4 of the 16 channels
    int t = tid >> 2;
    const int ow = t % WO; t /= WO;
    const int oh = t % HO;
    const int b  = t / HO;

    const size_t mbase = (size_t)b * H_IN * W_IN;
    const int ih0 = oh * 2, iw0 = ow * 2;

    // output-coord occupancy: any of the 2x2 strided block occupied
    const bool m00 = msk[mbase + (size_t)ih0 * W_IN + iw0] != 0;
    const bool m01 = msk[mbase + (size_t)ih0 * W_IN + iw0 + 1] != 0;
    const bool m10 = msk[mbase + (size_t)(ih0 + 1) * W_IN + iw0] != 0;
    const bool m11 = msk[mbase + (size_t)(ih0 + 1) * W_IN + iw0 + 1] != 0;
    const bool mo = m00 | m01 | m10 | m11;

    if (c4 == 0 && mout != nullptr)
        mout[(size_t)b * HO * WO + (size_t)oh * WO + ow] = mo ? 1 : 0;

    float4 acc = make_float4(0.f, 0.f, 0.f, 0.f);
    if (mo) {
#pragma unroll
        for (int dh = -1; dh <= 1; ++dh) {
            const int ih = ih0 + dh;
            if (ih < 0) continue;  // pad=1: only top edge can underflow
#pragma unroll
            for (int dw = -1; dw <= 1; ++dw) {
                const int iw = iw0 + dw;
                if (iw < 0) continue;
                bool valid = true;
                if (APPLY_MASK)
                    valid = msk[mbase + (size_t)ih * W_IN + iw] != 0;
                if (valid) {
                    const float4 v = *reinterpret_cast<const float4*>(
                        in + ((((size_t)b * H_IN + ih) * W_IN + iw) << 4) + (c4 << 2));
                    acc.x += v.x; acc.y += v.y; acc.z += v.z; acc.w += v.w;
                }
            }
        }
    }
    // unoccupied outputs are exact zeros (d_out is poisoned, must overwrite)
    float4* op = reinterpret_cast<float4*>(
        out + ((((size_t)b * HO + oh) * WO + ow) << 4) + (c4 << 2));
    *op = acc;
}

extern "C" void kernel_launch(void* const* d_in, const int* in_sizes, int n_in,
                              void* d_out, int out_size, void* d_ws, size_t ws_size,
                              hipStream_t stream)
{
    const float* feat = (const float*)d_in[0];
    const int*   mask = (const int*)d_in[1];

    float* c2 = (float*)d_out;                               // 4*256*256*16
    float* c3 = c2 + (size_t)BATCH * 256 * 256 * 16;         // 4*128*128*16

    char* ws = (char*)d_ws;
    float* c1 = (float*)ws;                                  // 64 MiB
    unsigned char* m1 = (unsigned char*)(ws + (size_t)BATCH * 512 * 512 * 16 * 4);
    unsigned char* m2 = m1 + (size_t)BATCH * 512 * 512;

    // stage 1: 1024 -> 512 (apply input mask to raw features)
    {
        const int total = BATCH * 512 * 512 * 4;
        pool3x3s2<1024, 1024, true, int>
            <<<total / 256, 256, 0, stream>>>(feat, mask, c1, m1);
    }
    // stage 2: 512 -> 256 (input already exact-zero at unoccupied coords)
    {
        const int total = BATCH * 256 * 256 * 4;
        pool3x3s2<512, 512, false, unsigned char>
            <<<total / 256, 256, 0, stream>>>(c1, m1, c2, m2);
    }
    // stage 3: 256 -> 128
    {
        const int total = BATCH * 128 * 128 * 4;
        pool3x3s2<256, 256, false, unsigned char>
            <<<total / 256, 256, 0, stream>>>(c2, m2, c3, nullptr);
    }
}

// Round 2
// 65.264 us; speedup vs baseline: 1.8236x; 1.8236x over previous
//
#include <hip/hip_runtime.h>

// Fully-fused 3x Minkowski sum-pool (3x3, stride 2, pad 1) with coordinate masks.
// feat (4,1024,1024,16) f32, mask (4,1024,1024) i32 -> out = concat(c2, c3).
// Line-buffer sweep: per block, walk feat rows; register histories carry the
// vertical 3-row windows at every level; LDS carries only the strided
// horizontal handoffs (c1m, c2m) plus 1-byte mask lines.

constexpr int Hh = 1024, Ww = 1024;
constexpr int TW3 = 16, TH3 = 8;           // c3 tile per block
constexpr int NU = 4 * TW3 + 3;            // 67 c1 cols computed per block
constexpr int NV = 2 * TW3 + 1;            // 33 c2 cols computed per block
constexpr int NY = TW3;                    // 16 c3 cols
constexpr int NTH = 320;

// LDS-only barrier: wait own LDS ops, sync, but leave global prefetch in flight.
#define BARRIER_LDS() asm volatile("s_waitcnt lgkmcnt(0)\ns_barrier" ::: "memory")

__device__ inline float4 add3(const float4& a, const float4& b, const float4& c) {
    return make_float4(a.x + b.x + c.x, a.y + b.y + c.y,
                       a.z + b.z + c.z, a.w + b.w + c.w);
}

__global__ __launch_bounds__(NTH) void fused3(
    const float* __restrict__ featp, const int* __restrict__ maskp,
    float4* __restrict__ c2o, float4* __restrict__ c3o)
{
    const int j = blockIdx.x;              // col strip (c3 cols [16j,16j+16))
    const int k = blockIdx.y;              // row chunk (c3 rows [8k,8k+8))
    const int b = blockIdx.z;
    const int P0 = TW3 * j, Q0 = TH3 * k;
    const int F0 = 8 * P0 - 7;             // feat col of relative x=0
    const int T0 = 8 * Q0 - 7;             // first feat row of sweep (odd)

    const int tid = threadIdx.x;
    const int c4 = tid & 3;                // which float4 of 16 channels
    const int u  = tid >> 2;               // c1-col / c2-col / c3-col role index
    const bool aAct = tid < NU * 4;        // 268 threads: rs1/c1 role
    const bool vAct = tid < NV * 4;        // 132 threads: rs2/c2 role
    const bool yAct = tid < NY * 4;        //  64 threads: rs3/c3 role

    // double-buffered handoffs; inner stride 5 float4 (80 B) to spread banks
    __shared__ float4 c1m[2][NU][5];
    __shared__ float4 c2mS[2][NV][5];
    __shared__ unsigned char m1L[2][NU];
    __shared__ unsigned char m2L[2][NV];

    const float4* feat4 = reinterpret_cast<const float4*>(featp);
    const float4 z4 = make_float4(0.f, 0.f, 0.f, 0.f);

    auto ldMask = [&](int t, int* mm) {
#pragma unroll
        for (int dw = 0; dw < 3; ++dw) mm[dw] = 0;
        if (aAct && (unsigned)t < (unsigned)Hh) {
            const int base = (b * Hh + t) * Ww;
#pragma unroll
            for (int dw = 0; dw < 3; ++dw) {
                const int fcol = F0 + 2 * u + dw;
                if ((unsigned)fcol < (unsigned)Ww) mm[dw] = maskp[base + fcol];
            }
        }
    };
    auto ldFeat = [&](int t, const int* mm, float4* ff) {
#pragma unroll
        for (int dw = 0; dw < 3; ++dw) ff[dw] = z4;
        if (aAct && (unsigned)t < (unsigned)Hh) {
            const size_t base = (size_t)(b * Hh + t) * Ww;
#pragma unroll
            for (int dw = 0; dw < 3; ++dw) {
                const int fcol = F0 + 2 * u + dw;
                if (mm[dw])  // masked-out pixels are never fetched
                    ff[dw] = feat4[(base + fcol) * 4 + c4];
            }
        }
    };

    // software pipeline: masks 2 rows ahead (they gate feat loads 1 row ahead)
    int mc[3], mn[3], mn2[3];
    float4 fcu[3], fn[3];
    ldMask(T0, mc);
    ldFeat(T0, mc, fcu);
    ldMask(T0 + 1, mn);

    float4 h0 = z4, h1 = z4;               // rs1 history rows t-2, t-1
    int mpPrev = 0;                        // mask-pair (pixels 2u+1,2u+2) of row t-1
    float4 r2h0 = z4, r2h1 = z4;           // rs2 history (s-2, s-1)
    float4 r3h0 = z4, r3h1 = z4;           // rs3 history (r-2, r-1)
    int m2save = 0, m3save = 0;

    for (int tt = 0; tt <= 70; ++tt) {
        const int t = T0 + tt;             // feat row being consumed
        if (tt <= 68) ldMask(t + 2, mn2);
        else { mn2[0] = mn2[1] = mn2[2] = 0; }
        if (tt <= 69) ldFeat(t + 1, mn, fn);
        else { fn[0] = fn[1] = fn[2] = z4; }

        // rs1[t][u] = sum_dw masked_feat[t][2u+dw]  (fcu already mask-zeroed)
        const float4 hc = add3(fcu[0], fcu[1], fcu[2]);
        const int mpCur = mc[1] | mc[2];   // mask pair for m1 (pixels 2u+1,2u+2)

        if (t & 1) {                       // c1 row s completes
            const int s = (t - 1) >> 1;
            const int sb = s & 1;
            if (aAct) {
                const int m1 = mpPrev | mpCur;
                float4 cv = z4;
                if (m1) cv = add3(h0, h1, hc);          // c1 = col-sum of rs1
                c1m[sb][u][c4] = cv;                    // masked c1 handoff
                if (c4 == 0) m1L[sb][u] = (unsigned char)(m1 ? 1 : 0);
            }
            BARRIER_LDS();
            float4 r2c = z4; int m2 = 0;
            if (vAct) {                    // rs2[s][v] = sum_dw c1m[s][2v+dw]
                const float4 a0 = c1m[sb][2 * u + 0][c4];
                const float4 a1 = c1m[sb][2 * u + 1][c4];
                const float4 a2 = c1m[sb][2 * u + 2][c4];
                r2c = add3(a0, a1, a2);
                const int m2p = m1L[sb][2 * u + 1] | m1L[sb][2 * u + 2];
                if (s & 1) m2 = m2save | m2p; else m2save = m2p;
            }
            if ((t & 3) == 3) {            // c2 row r completes
                const int r = (t - 3) >> 2;
                const int rb = r & 1;
                if (vAct) {
                    float4 c2v = z4;
                    if (m2) c2v = add3(r2h0, r2h1, r2c);
                    if (r >= 2 * Q0 && u >= 1) {        // owned c2 rows/cols
                        const int col = 2 * P0 - 1 + u;
                        c2o[((size_t)((b * 256 + r) * 256 + col)) * 4 + c4] = c2v;
                    }
                    c2mS[rb][u][c4] = c2v;
                    if (c4 == 0) m2L[rb][u] = (unsigned char)(m2 ? 1 : 0);
                }
                BARRIER_LDS();
                float4 r3c = z4; int m3 = 0;
                if (yAct) {                // rs3[r][y] = sum_dw c2m[r][2y+dw]
                    const float4 b0 = c2mS[rb][2 * u + 0][c4];
                    const float4 b1 = c2mS[rb][2 * u + 1][c4];
                    const float4 b2 = c2mS[rb][2 * u + 2][c4];
                    r3c = add3(b0, b1, b2);
                    const int m3p = m2L[rb][2 * u + 1] | m2L[rb][2 * u + 2];
                    if (r & 1) m3 = m3save | m3p; else m3save = m3p;
                }
                if ((t & 7) == 7) {        // c3 row q completes
                    const int q = (t - 7) >> 3;
                    if (yAct && q >= Q0) {
                        float4 c3v = z4;
                        if (m3) c3v = add3(r3h0, r3h1, r3c);
                        c3o[((size_t)((b * 128 + q) * 128 + P0 + u)) * 4 + c4] = c3v;
                    }
                }
                r3h0 = r3h1; r3h1 = r3c;
            }
            r2h0 = r2h1; r2h1 = r2c;
        }

        h0 = h1; h1 = hc;
        mpPrev = mpCur;
        fcu[0] = fn[0]; fcu[1] = fn[1]; fcu[2] = fn[2];
        mc[0] = mn[0]; mc[1] = mn[1]; mc[2] = mn[2];
        mn[0] = mn2[0]; mn[1] = mn2[1]; mn[2] = mn2[2];
    }
}

extern "C" void kernel_launch(void* const* d_in, const int* in_sizes, int n_in,
                              void* d_out, int out_size, void* d_ws, size_t ws_size,
                              hipStream_t stream)
{
    const float* feat = (const float*)d_in[0];
    const int*   mask = (const int*)d_in[1];
    float4* c2 = (float4*)d_out;
    float4* c3 = c2 + (size_t)4 * 256 * 256 * 4;   // 4*256*256*16 floats ahead

    dim3 grid(Ww / (8 * TW3) /*8*/, Hh / (8 * TH3) /*16*/, 4);
    fused3<<<grid, NTH, 0, stream>>>(feat, mask, c2, c3);
}